// Round 1
// 347.160 us; speedup vs baseline: 1.0727x; 1.0727x over previous
//
#include <hip/hip_runtime.h>

typedef unsigned short u16;
typedef unsigned int u32;
typedef __attribute__((ext_vector_type(8))) short short8;
typedef __attribute__((ext_vector_type(4))) float floatx4;

#define HEADS 8
#define DIM 512          // K for both GEMMs
#define HH 96
#define WW 96
#define NPIX 9216
#define M_TOT 36864
#define N_QKV 1536
#define SCALE 0.125f

__device__ __forceinline__ float b2f(u16 v){
    union{float f;u32 u;}x; x.u=((u32)v)<<16; return x.f;
}
__device__ __forceinline__ u16 f2b(float f){
    union{float f;u32 u;}x; x.f=f;
    u32 u=x.u + 0x7fffu + ((x.u>>16)&1u);
    return (u16)(u>>16);
}
__device__ __forceinline__ u32 pack2(float a,float b){
    return (u32)f2b(a) | ((u32)f2b(b)<<16);
}

// async global->LDS, 16 B per lane; lds dest = wave-uniform base + lane*16
__device__ __forceinline__ void gload16(const u16* g, u16* l){
    __builtin_amdgcn_global_load_lds(
        (const __attribute__((address_space(1))) u32*)g,
        (__attribute__((address_space(3))) u32*)l, 16, 0, 0);
}

// ---------------------------------------------------------------------------
// dtype detector (bf16 vs fp32 inputs)
// ---------------------------------------------------------------------------
__global__ void detect_dtype(const u16* __restrict__ wq, int* __restrict__ flag){
    __shared__ int cnt;
    if (threadIdx.x==0) cnt=0;
    __syncthreads();
    u16 u = wq[2*threadIdx.x];
    int e = (u>>7)&0xff;
    if (e>=100 && e<=128) atomicAdd(&cnt,1);
    __syncthreads();
    if (threadIdx.x==0) *flag = (cnt>128)?1:0;
}

// ---------------------------------------------------------------------------
// Weights -> bf16 (layout unchanged, [n][k] k-contiguous)
// ---------------------------------------------------------------------------
__global__ __launch_bounds__(256)
void convert_w(const void* __restrict__ wq, const void* __restrict__ wo,
               const int* __restrict__ flag, u16* __restrict__ wqb, u16* __restrict__ wob){
    const int isb = *flag;
    int i = blockIdx.x*256 + threadIdx.x;
    const int nq = N_QKV*DIM;                 // 786432
    if (i < nq){
        wqb[i] = isb ? ((const u16*)wq)[i] : f2b(((const float*)wq)[i]);
    } else {
        int j = i - nq;                       // < 262144
        wob[j] = isb ? ((const u16*)wo)[j] : f2b(((const float*)wo)[j]);
    }
}

// ---------------------------------------------------------------------------
// x [b][c][pix] (fp32 or bf16) -> xb [b*9216+pix][c] bf16   (transpose)
// ---------------------------------------------------------------------------
__global__ __launch_bounds__(256)
void convert_x(const void* __restrict__ xv, const int* __restrict__ flag,
               u16* __restrict__ xb){
    __shared__ u16 tile[64][65];
    const int isb = *flag;
    const int p0 = blockIdx.x*64, c0 = blockIdx.y*64, b = blockIdx.z;
    const int t = threadIdx.x;
    const int pl = t&63, c4 = t>>6;
    const float* x32 = (const float*)xv;
    const u16*   x16 = (const u16*)xv;
    size_t src = ((size_t)b*DIM + c0 + c4)*NPIX + p0 + pl;
    #pragma unroll
    for (int i=0;i<16;i++){
        int cl = c4 + i*4;
        size_t s = src + (size_t)i*4*NPIX;
        tile[cl][pl] = isb ? x16[s] : f2b(x32[s]);
    }
    __syncthreads();
    const int cu = t&31, r8 = t>>5;
    u32* xb32 = (u32*)xb;
    #pragma unroll
    for (int i=0;i<8;i++){
        int pr = r8 + i*8;
        u32 v = (u32)tile[2*cu][pr] | ((u32)tile[2*cu+1][pr]<<16);
        xb32[((size_t)b*NPIX + p0 + pr)*(DIM/2) + (c0>>1) + cu] = v;
    }
}

// ---------------------------------------------------------------------------
// MFMA GEMM 1: 256x256 tile, BK=64, 8 waves (2M x 4N), double-buffered LDS
// with counted vmcnt (T3+T4) + setprio (T5). LDS layout is chunked
// fragment-contiguous (16rows x 32k chunks, lane*16B) -> conflict-free,
// and global_load_lds-compatible (linear dest). 2 raw barriers per K-tile,
// 64 MFMA/wave between barrier pairs, vmcnt(2) in steady state (never 0).
//
// bx<4 (Q,K) -> qk_ws[m][1024] bf16.  bx>=4 (V) -> vt[(b*8+h)*64+d][pix].
// Grid 864 = 8 XCDs x 108; blocks sharing an A-panel land on one XCD.
// ---------------------------------------------------------------------------
__global__ __launch_bounds__(512, 2)
void gemm_qkv(const u16* __restrict__ A, const u16* __restrict__ B,
              u16* __restrict__ Cqk, u16* __restrict__ vt){
    __shared__ __align__(16) union ShMem {
        u16 tiles[65536];            // 2 bufs x (A 16384 + B 16384) u16 = 128 KiB
        float ctQ[8][16][68];        // per-wave epilogue transpose (Q,K)
        float ctV[8][16][132];       // per-wave epilogue transpose (V)
    } sh;
    u16* lds = sh.tiles;
    const int id = blockIdx.x;
    const int xcd = id & 7, slot = id >> 3;        // 864 = 8 x 108
    const int q6 = slot/6;
    const int by = xcd*18 + q6;                    // same A-panel -> same XCD
    const int bx = slot - q6*6;
    const int t = threadIdx.x;
    const int w = t>>6, l = t&63, lr = l&15, lq = l>>4;
    const int wm2 = w>>2, wn4 = w&3;               // wave = 128(M) x 64(N)
    const int m0 = by*256, n0 = bx*256;
    const u16* gA0 = A + (size_t)(m0 +       w*16 + lr)*DIM + lq*8;
    const u16* gA1 = A + (size_t)(m0 + 128 + w*16 + lr)*DIM + lq*8;
    const u16* gB0 = B + (size_t)(n0 +       w*16 + lr)*DIM + lq*8;
    const u16* gB1 = B + (size_t)(n0 + 128 + w*16 + lr)*DIM + lq*8;

    // stage one half-tile (128 rows x 64 k of one operand): 2 gloads/thread.
    // chunk(sub,ks) lives at u16 offset (sub*2+ks)*512; sub = h*8 + w.
#define STG(gp, opb, h, ko, bb) do { \
        const u16* _g = (gp) + (ko); \
        u16* _l = lds + (bb)*32768 + (opb) + ((h)*8 + w)*1024; \
        gload16(_g,      _l); \
        gload16(_g + 32, _l + 512); \
    } while(0)

    floatx4 acc[8][4] = {};
    // prologue: tile 0 -> buf 0 (8 gloads/thread)
    STG(gA0, 0,     0, 0, 0);
    STG(gA1, 0,     1, 0, 0);
    STG(gB0, 16384, 0, 0, 0);
    STG(gB1, 16384, 1, 0, 0);

    #pragma unroll 1
    for (int ktile=0; ktile<8; ++ktile){
        const int cur = ktile&1, nxt = cur^1;
        const int ko = (ktile+1)*64;               // next tile k-offset (u16)
        if (ktile < 7){
            STG(gA0, 0, 0, ko, nxt);               // A staged earliest (HBM)
            asm volatile("s_waitcnt vmcnt(2)" ::: "memory");  // tile k landed
        } else {
            asm volatile("s_waitcnt vmcnt(0)" ::: "memory");
        }
        __builtin_amdgcn_s_barrier();
        asm volatile("" ::: "memory");
        const u16* bA = lds + cur*32768 +         wm2*8192 + l*8;
        const u16* bB = lds + cur*32768 + 16384 + wn4*4096 + l*8;
        short8 af[4][2], bf[2][2];
        // ---- phase 0: quadrant (mh=0, nh=0)
        #pragma unroll
        for (int mi=0;mi<4;mi++){
            af[mi][0] = *(const short8*)(bA + mi*1024);
            af[mi][1] = *(const short8*)(bA + mi*1024 + 512);
        }
        #pragma unroll
        for (int ni=0;ni<2;ni++){
            bf[ni][0] = *(const short8*)(bB + ni*1024);
            bf[ni][1] = *(const short8*)(bB + ni*1024 + 512);
        }
        if (ktile < 7) STG(gA1, 0, 1, ko, nxt);
        __builtin_amdgcn_s_setprio(1);
        #pragma unroll
        for (int mi=0;mi<4;mi++)
            #pragma unroll
            for (int ni=0;ni<2;ni++){
                acc[mi][ni] = __builtin_amdgcn_mfma_f32_16x16x32_bf16(af[mi][0], bf[ni][0], acc[mi][ni], 0,0,0);
                acc[mi][ni] = __builtin_amdgcn_mfma_f32_16x16x32_bf16(af[mi][1], bf[ni][1], acc[mi][ni], 0,0,0);
            }
        __builtin_amdgcn_s_setprio(0);
        // ---- phase 1: quadrant (0,1) — reuse A-lo, read B-hi
        #pragma unroll
        for (int ni=0;ni<2;ni++){
            bf[ni][0] = *(const short8*)(bB + (2+ni)*1024);
            bf[ni][1] = *(const short8*)(bB + (2+ni)*1024 + 512);
        }
        if (ktile < 7) STG(gB0, 16384, 0, ko, nxt);
        __builtin_amdgcn_s_setprio(1);
        #pragma unroll
        for (int mi=0;mi<4;mi++)
            #pragma unroll
            for (int ni=0;ni<2;ni++){
                acc[mi][2+ni] = __builtin_amdgcn_mfma_f32_16x16x32_bf16(af[mi][0], bf[ni][0], acc[mi][2+ni], 0,0,0);
                acc[mi][2+ni] = __builtin_amdgcn_mfma_f32_16x16x32_bf16(af[mi][1], bf[ni][1], acc[mi][2+ni], 0,0,0);
            }
        __builtin_amdgcn_s_setprio(0);
        // ---- phase 2: quadrant (1,1) — reuse B-hi, read A-hi
        #pragma unroll
        for (int mi=0;mi<4;mi++){
            af[mi][0] = *(const short8*)(bA + (4+mi)*1024);
            af[mi][1] = *(const short8*)(bA + (4+mi)*1024 + 512);
        }
        if (ktile < 7) STG(gB1, 16384, 1, ko, nxt);
        __builtin_amdgcn_s_setprio(1);
        #pragma unroll
        for (int mi=0;mi<4;mi++)
            #pragma unroll
            for (int ni=0;ni<2;ni++){
                acc[4+mi][2+ni] = __builtin_amdgcn_mfma_f32_16x16x32_bf16(af[mi][0], bf[ni][0], acc[4+mi][2+ni], 0,0,0);
                acc[4+mi][2+ni] = __builtin_amdgcn_mfma_f32_16x16x32_bf16(af[mi][1], bf[ni][1], acc[4+mi][2+ni], 0,0,0);
            }
        __builtin_amdgcn_s_setprio(0);
        // ---- phase 3: quadrant (1,0) — reuse A-hi, re-read B-lo
        #pragma unroll
        for (int ni=0;ni<2;ni++){
            bf[ni][0] = *(const short8*)(bB + ni*1024);
            bf[ni][1] = *(const short8*)(bB + ni*1024 + 512);
        }
        __builtin_amdgcn_s_setprio(1);
        #pragma unroll
        for (int mi=0;mi<4;mi++)
            #pragma unroll
            for (int ni=0;ni<2;ni++){
                acc[4+mi][ni] = __builtin_amdgcn_mfma_f32_16x16x32_bf16(af[mi][0], bf[ni][0], acc[4+mi][ni], 0,0,0);
                acc[4+mi][ni] = __builtin_amdgcn_mfma_f32_16x16x32_bf16(af[mi][1], bf[ni][1], acc[4+mi][ni], 0,0,0);
            }
        __builtin_amdgcn_s_setprio(0);
        asm volatile("" ::: "memory");
        __builtin_amdgcn_s_barrier();              // buf[cur] reads done
        asm volatile("" ::: "memory");
    }
#undef STG
    if (bx < 4){
        // Q,K epilogue: per-wave LDS transpose -> 2x dwordx4 store per mi
        float (*ct)[68] = sh.ctQ[w];
        const int row = l>>2, cg = l&3;
        u16* dstbase = Cqk + (size_t)(m0 + wm2*128)*1024 + n0 + wn4*64 + cg*16;
        #pragma unroll
        for (int mi=0;mi<8;mi++){
            #pragma unroll
            for (int ni=0;ni<4;ni++)
                #pragma unroll
                for (int r=0;r<4;r++)
                    ct[lq*4+r][ni*16+lr] = acc[mi][ni][r];
            // per-wave buffer: DS in-order within wave, no barrier needed
            const float* cp = &ct[row][cg*16];
            float4 v0 = *(const float4*)(cp);
            float4 v1 = *(const float4*)(cp+4);
            float4 v2 = *(const float4*)(cp+8);
            float4 v3 = *(const float4*)(cp+12);
            uint4 s0, s1;
            s0.x=pack2(v0.x,v0.y); s0.y=pack2(v0.z,v0.w);
            s0.z=pack2(v1.x,v1.y); s0.w=pack2(v1.z,v1.w);
            s1.x=pack2(v2.x,v2.y); s1.y=pack2(v2.z,v2.w);
            s1.z=pack2(v3.x,v3.y); s1.w=pack2(v3.z,v3.w);
            u16* dst = dstbase + (size_t)(mi*16 + row)*1024;
            *((uint4*)dst)     = s0;
            *((uint4*)(dst+8)) = s1;
        }
    } else {
        // V epilogue: transposed into vt[(bh*64+d)][pix], 4x dwordx4/lane
        float (*ct)[132] = sh.ctV[w];
        const int bat  = m0 / NPIX;
        const int pixb = m0 - bat*NPIX + wm2*128;
        const int nl = l>>2, seg = l&3;
        for (int ni=0; ni<4; ni++){
            #pragma unroll
            for (int mi=0;mi<8;mi++)
                #pragma unroll
                for (int r=0;r<4;r++)
                    ct[lr][mi*16 + lq*4 + r] = acc[mi][ni][r];
            int ch  = n0 + wn4*64 + ni*16 + nl - 1024;   // head*64+d
            int bh2 = bat*8 + (ch>>6);
            int dd  = ch & 63;
            const float* cp = &ct[nl][seg*32];
            float4 v0 = *(const float4*)(cp);
            float4 v1 = *(const float4*)(cp+4);
            float4 v2 = *(const float4*)(cp+8);
            float4 v3 = *(const float4*)(cp+12);
            float4 v4 = *(const float4*)(cp+16);
            float4 v5 = *(const float4*)(cp+20);
            float4 v6 = *(const float4*)(cp+24);
            float4 v7 = *(const float4*)(cp+28);
            uint4 s0, s1, s2, s3;
            s0.x=pack2(v0.x,v0.y); s0.y=pack2(v0.z,v0.w);
            s0.z=pack2(v1.x,v1.y); s0.w=pack2(v1.z,v1.w);
            s1.x=pack2(v2.x,v2.y); s1.y=pack2(v2.z,v2.w);
            s1.z=pack2(v3.x,v3.y); s1.w=pack2(v3.z,v3.w);
            s2.x=pack2(v4.x,v4.y); s2.y=pack2(v4.z,v4.w);
            s2.z=pack2(v5.x,v5.y); s2.w=pack2(v5.z,v5.w);
            s3.x=pack2(v6.x,v6.y); s3.y=pack2(v6.z,v6.w);
            s3.z=pack2(v7.x,v7.y); s3.w=pack2(v7.z,v7.w);
            u16* dst = vt + (size_t)(bh2*64+dd)*NPIX + pixb + seg*32;
            *((uint4*)dst)      = s0;
            *((uint4*)(dst+8))  = s1;
            *((uint4*)(dst+16)) = s2;
            *((uint4*)(dst+24)) = s3;
        }
    }
}

// ---------------------------------------------------------------------------
// Kernel 2: width-axis MFMA attention. One block per (b, head, row), 4 waves.
// ---------------------------------------------------------------------------
__global__ __launch_bounds__(256)
void attn_kernel(const u16* __restrict__ qk, const u16* __restrict__ vt,
                 u16* __restrict__ attno){
    __shared__ __align__(16) u16 Qf[6144];   // Q frag tiles; later V^T tiles
    __shared__ __align__(16) u16 Pb[9984];   // K frags; later P bf16 [96][104]; later O [96][72]
    __shared__ float Ss[96][97];
    __shared__ float smax[96][2], ssum[96][2], rinv[96];
    const int t = threadIdx.x;
    const int w = t>>6, l = t&63, lr = l&15, lq = l>>4;
    const int wm = w&1, wn = w>>1;
    const int blk = blockIdx.x;              // 3072
    const int row  = blk % HH;
    const int bh   = blk / HH;               // bat*8 + head
    const int head = bh & 7;
    const int bat  = bh >> 3;
    const size_t pixrow = (size_t)bat*NPIX + row*WW;
    const u16* qbase = qk + pixrow*1024 + head*64;
    #pragma unroll
    for (int i=0;i<6;i++){
        int c  = w*6 + i;
        int c2 = (c<12) ? c : (c-12);
        int mt = c2>>1, ks = c2&1;
        const u16* g = qbase + (size_t)(mt*16+lr)*1024 + ks*32 + lq*8 + ((c<12)?0:512);
        u16* dst = ((c<12)?Qf:Pb) + c2*512 + l*8;
        gload16(g, dst);
    }
    __syncthreads();
    {
        floatx4 acc[3][3] = {};
        #pragma unroll
        for (int ks=0;ks<2;ks++){
            short8 af[3], bf[3];
            #pragma unroll
            for (int i=0;i<3;i++) af[i] = *(const short8*)&Qf[((wm*3+i)*2+ks)*512 + l*8];
            #pragma unroll
            for (int j=0;j<3;j++) bf[j] = *(const short8*)&Pb[((wn*3+j)*2+ks)*512 + l*8];
            #pragma unroll
            for (int i=0;i<3;i++)
                #pragma unroll
                for (int j=0;j<3;j++)
                    acc[i][j] = __builtin_amdgcn_mfma_f32_16x16x32_bf16(af[i], bf[j], acc[i][j], 0,0,0);
        }
        #pragma unroll
        for (int i=0;i<3;i++)
            #pragma unroll
            for (int j=0;j<3;j++)
                #pragma unroll
                for (int r=0;r<4;r++)
                    Ss[(wm*3+i)*16 + lq*4 + r][(wn*3+j)*16 + lr] = acc[i][j][r]*SCALE;
    }
    __syncthreads();
    #pragma unroll
    for (int i=0;i<3;i++){
        const u16* g = vt + (size_t)(bh*64 + w*16 + lr)*NPIX + row*WW + i*32 + lq*8;
        gload16(g, Qf + (w*3+i)*512 + l*8);
    }
    const int srow = t>>1, shalf = t&1, sbase = shalf*48;
    if (t < 192){
        float m = -1e30f;
        #pragma unroll 8
        for (int j=0;j<48;j++) m = fmaxf(m, Ss[srow][sbase+j]);
        smax[srow][shalf] = m;
    }
    __syncthreads();   // smax ready; also drains V^T staging (vmcnt)
    if (t < 192){
        float m2 = fmaxf(smax[srow][0], smax[srow][1]);
        float s = 0.f;
        u32* prow = (u32*)&Pb[srow*104 + sbase];
        #pragma unroll 8
        for (int j=0;j<48;j+=2){
            float e0 = __expf(Ss[srow][sbase+j]   - m2);
            float e1 = __expf(Ss[srow][sbase+j+1] - m2);
            prow[j>>1] = pack2(e0, e1);
            s += e0 + e1;
        }
        ssum[srow][shalf] = s;
    }
    __syncthreads();
    if (t < 192 && shalf==0) rinv[srow] = 1.f/(ssum[srow][0]+ssum[srow][1]);
    floatx4 o[3][2] = {};
    #pragma unroll
    for (int ks2=0;ks2<3;ks2++){
        short8 bf2[2];
        #pragma unroll
        for (int bb=0;bb<2;bb++)
            bf2[bb] = *(const short8*)&Qf[((wn*2+bb)*3+ks2)*512 + l*8];
        #pragma unroll
        for (int aa=0;aa<3;aa++){
            short8 af = *(const short8*)&Pb[((wm*3+aa)*16+lr)*104 + ks2*32 + lq*8];
            #pragma unroll
            for (int bb=0;bb<2;bb++)
                o[aa][bb] = __builtin_amdgcn_mfma_f32_16x16x32_bf16(af, bf2[bb], o[aa][bb], 0,0,0);
        }
    }
    __syncthreads();   // PV reads of Pb done; rinv visible
    #pragma unroll
    for (int aa=0;aa<3;aa++){
        #pragma unroll
        for (int r=0;r<4;r++){
            int m = (wm*3+aa)*16 + lq*4 + r;
            float rv = rinv[m];
            int d0 = wn*32 + lr;
            Pb[m*72 + d0]      = f2b(o[aa][0][r]*rv);
            Pb[m*72 + d0 + 16] = f2b(o[aa][1][r]*rv);
        }
    }
    __syncthreads();
    #pragma unroll
    for (int i=0;i<3;i++){
        int idx = i*256 + t;                 // 768 = 96 rows x 8 segs
        int rr = idx>>3, seg = idx&7;
        uint4 vv = *(const uint4*)&Pb[rr*72 + seg*8];
        *(uint4*)(attno + (pixrow+rr)*512 + head*64 + seg*8) = vv;
    }
}

// ---------------------------------------------------------------------------
// MFMA GEMM 2: out[b][n][pix] = attn_ws[m][k] * wob[n][k] + bias[n]
// Same 256x256 counted-vmcnt schedule as gemm_qkv. Grid 288 = 8 x 36.
// ---------------------------------------------------------------------------
__global__ __launch_bounds__(512, 2)
void gemm_out(const u16* __restrict__ A, const u16* __restrict__ B,
              const void* __restrict__ bias, const int* __restrict__ flag,
              void* __restrict__ outv){
    __shared__ __align__(16) union ShMem {
        u16 tiles[65536];
        float ctV[8][16][132];
    } sh;
    u16* lds = sh.tiles;
    const int id = blockIdx.x;
    const int xcd = id & 7, slot = id >> 3;        // 288 = 8 x 36
    const int by = xcd*18 + (slot>>1);
    const int bx = slot & 1;
    const int t = threadIdx.x;
    const int w = t>>6, l = t&63, lr = l&15, lq = l>>4;
    const int wm2 = w>>2, wn4 = w&3;
    const int m0 = by*256, n0 = bx*256;
    const u16* gA0 = A + (size_t)(m0 +       w*16 + lr)*DIM + lq*8;
    const u16* gA1 = A + (size_t)(m0 + 128 + w*16 + lr)*DIM + lq*8;
    const u16* gB0 = B + (size_t)(n0 +       w*16 + lr)*DIM + lq*8;
    const u16* gB1 = B + (size_t)(n0 + 128 + w*16 + lr)*DIM + lq*8;

#define STG(gp, opb, h, ko, bb) do { \
        const u16* _g = (gp) + (ko); \
        u16* _l = lds + (bb)*32768 + (opb) + ((h)*8 + w)*1024; \
        gload16(_g,      _l); \
        gload16(_g + 32, _l + 512); \
    } while(0)

    floatx4 acc[8][4] = {};
    STG(gA0, 0,     0, 0, 0);
    STG(gA1, 0,     1, 0, 0);
    STG(gB0, 16384, 0, 0, 0);
    STG(gB1, 16384, 1, 0, 0);

    #pragma unroll 1
    for (int ktile=0; ktile<8; ++ktile){
        const int cur = ktile&1, nxt = cur^1;
        const int ko = (ktile+1)*64;
        if (ktile < 7){
            STG(gA0, 0, 0, ko, nxt);
            asm volatile("s_waitcnt vmcnt(2)" ::: "memory");
        } else {
            asm volatile("s_waitcnt vmcnt(0)" ::: "memory");
        }
        __builtin_amdgcn_s_barrier();
        asm volatile("" ::: "memory");
        const u16* bA = lds + cur*32768 +         wm2*8192 + l*8;
        const u16* bB = lds + cur*32768 + 16384 + wn4*4096 + l*8;
        short8 af[4][2], bf[2][2];
        #pragma unroll
        for (int mi=0;mi<4;mi++){
            af[mi][0] = *(const short8*)(bA + mi*1024);
            af[mi][1] = *(const short8*)(bA + mi*1024 + 512);
        }
        #pragma unroll
        for (int ni=0;ni<2;ni++){
            bf[ni][0] = *(const short8*)(bB + ni*1024);
            bf[ni][1] = *(const short8*)(bB + ni*1024 + 512);
        }
        if (ktile < 7) STG(gA1, 0, 1, ko, nxt);
        __builtin_amdgcn_s_setprio(1);
        #pragma unroll
        for (int mi=0;mi<4;mi++)
            #pragma unroll
            for (int ni=0;ni<2;ni++){
                acc[mi][ni] = __builtin_amdgcn_mfma_f32_16x16x32_bf16(af[mi][0], bf[ni][0], acc[mi][ni], 0,0,0);
                acc[mi][ni] = __builtin_amdgcn_mfma_f32_16x16x32_bf16(af[mi][1], bf[ni][1], acc[mi][ni], 0,0,0);
            }
        __builtin_amdgcn_s_setprio(0);
        #pragma unroll
        for (int ni=0;ni<2;ni++){
            bf[ni][0] = *(const short8*)(bB + (2+ni)*1024);
            bf[ni][1] = *(const short8*)(bB + (2+ni)*1024 + 512);
        }
        if (ktile < 7) STG(gB0, 16384, 0, ko, nxt);
        __builtin_amdgcn_s_setprio(1);
        #pragma unroll
        for (int mi=0;mi<4;mi++)
            #pragma unroll
            for (int ni=0;ni<2;ni++){
                acc[mi][2+ni] = __builtin_amdgcn_mfma_f32_16x16x32_bf16(af[mi][0], bf[ni][0], acc[mi][2+ni], 0,0,0);
                acc[mi][2+ni] = __builtin_amdgcn_mfma_f32_16x16x32_bf16(af[mi][1], bf[ni][1], acc[mi][2+ni], 0,0,0);
            }
        __builtin_amdgcn_s_setprio(0);
        #pragma unroll
        for (int mi=0;mi<4;mi++){
            af[mi][0] = *(const short8*)(bA + (4+mi)*1024);
            af[mi][1] = *(const short8*)(bA + (4+mi)*1024 + 512);
        }
        if (ktile < 7) STG(gB1, 16384, 1, ko, nxt);
        __builtin_amdgcn_s_setprio(1);
        #pragma unroll
        for (int mi=0;mi<4;mi++)
            #pragma unroll
            for (int ni=0;ni<2;ni++){
                acc[4+mi][2+ni] = __builtin_amdgcn_mfma_f32_16x16x32_bf16(af[mi][0], bf[ni][0], acc[4+mi][2+ni], 0,0,0);
                acc[4+mi][2+ni] = __builtin_amdgcn_mfma_f32_16x16x32_bf16(af[mi][1], bf[ni][1], acc[4+mi][2+ni], 0,0,0);
            }
        __builtin_amdgcn_s_setprio(0);
        #pragma unroll
        for (int ni=0;ni<2;ni++){
            bf[ni][0] = *(const short8*)(bB + ni*1024);
            bf[ni][1] = *(const short8*)(bB + ni*1024 + 512);
        }
        __builtin_amdgcn_s_setprio(1);
        #pragma unroll
        for (int mi=0;mi<4;mi++)
            #pragma unroll
            for (int ni=0;ni<2;ni++){
                acc[4+mi][ni] = __builtin_amdgcn_mfma_f32_16x16x32_bf16(af[mi][0], bf[ni][0], acc[4+mi][ni], 0,0,0);
                acc[4+mi][ni] = __builtin_amdgcn_mfma_f32_16x16x32_bf16(af[mi][1], bf[ni][1], acc[4+mi][ni], 0,0,0);
            }
        __builtin_amdgcn_s_setprio(0);
        asm volatile("" ::: "memory");
        __builtin_amdgcn_s_barrier();
        asm volatile("" ::: "memory");
    }
#undef STG
    const int isb = *flag;
    const int bat  = m0 / NPIX;
    const int pix0 = m0 - bat*NPIX + wm2*128;
    float (*ct)[132] = sh.ctV[w];
    const u16*   b16 = (const u16*)bias;
    const float* b32 = (const float*)bias;
    const int nl = l>>3, seg8 = l&7;
    for (int ni=0; ni<4; ni++){
        #pragma unroll
        for (int mi=0;mi<8;mi++)
            #pragma unroll
            for (int r=0;r<4;r++)
                ct[lr][mi*16 + lq*4 + r] = acc[mi][ni][r];
        #pragma unroll
        for (int p=0;p<2;p++){
            int nrow = nl + p*8;
            int ng = n0 + wn4*64 + ni*16 + nrow;
            float bv = isb ? b2f(b16[ng]) : b32[ng];
            const float* cp = &ct[nrow][seg8*16];
            float4 v0 = *(const float4*)(cp);
            float4 v1 = *(const float4*)(cp+4);
            float4 v2 = *(const float4*)(cp+8);
            float4 v3 = *(const float4*)(cp+12);
            v0.x+=bv; v0.y+=bv; v0.z+=bv; v0.w+=bv;
            v1.x+=bv; v1.y+=bv; v1.z+=bv; v1.w+=bv;
            v2.x+=bv; v2.y+=bv; v2.z+=bv; v2.w+=bv;
            v3.x+=bv; v3.y+=bv; v3.z+=bv; v3.w+=bv;
            size_t off = ((size_t)(bat*DIM + ng))*NPIX + pix0 + seg8*16;
            if (isb){
                uint4 s0, s1;
                s0.x=pack2(v0.x,v0.y); s0.y=pack2(v0.z,v0.w);
                s0.z=pack2(v1.x,v1.y); s0.w=pack2(v1.z,v1.w);
                s1.x=pack2(v2.x,v2.y); s1.y=pack2(v2.z,v2.w);
                s1.z=pack2(v3.x,v3.y); s1.w=pack2(v3.z,v3.w);
                *(uint4*)((u16*)outv + off)     = s0;
                *(uint4*)((u16*)outv + off + 8) = s1;
            } else {
                float* of = (float*)outv + off;
                *(float4*)(of)    = v0;
                *(float4*)(of+4)  = v1;
                *(float4*)(of+8)  = v2;
                *(float4*)(of+12) = v3;
            }
        }
    }
}

extern "C" void kernel_launch(void* const* d_in, const int* in_sizes, int n_in,
                              void* d_out, int out_size, void* d_ws, size_t ws_size,
                              hipStream_t stream){
    const void* x    = d_in[0];
    const void* wqkv = d_in[1];
    const void* wout = d_in[2];
    const void* bout = d_in[3];
    char* wsb = (char*)d_ws;
    int* flag    = (int*)wsb;                                  // 256 B
    u16* xb      = (u16*)(wsb + 256);                          // [36864][512] bf16
    u16* attn_ws = xb;                                         // alias: xb dead after gemm1
    u16* wqb     = xb + (size_t)M_TOT*DIM;                     // [1536][512]
    u16* wob     = wqb + (size_t)N_QKV*DIM;                    // [512][512]
    u16* qk_ws   = wob + (size_t)DIM*DIM;                      // [36864][1024] (Q,K)
    u16* vt_ws   = qk_ws + (size_t)M_TOT*1024;                 // [32*64][9216] (V^T)
    detect_dtype<<<1, 256, 0, stream>>>((const u16*)wqkv, flag);
    convert_w<<<4096, 256, 0, stream>>>(wqkv, wout, flag, wqb, wob);
    convert_x<<<dim3(144, 8, 4), 256, 0, stream>>>(x, flag, xb);
    gemm_qkv<<<864, 512, 0, stream>>>(xb, wqb, qk_ws, vt_ws);
    attn_kernel<<<3072, 256, 0, stream>>>(qk_ws, vt_ws, attn_ws);
    gemm_out<<<288, 512, 0, stream>>>(attn_ws, wob, bout, flag, d_out);
}